// Round 4
// baseline (11658.693 us; speedup 1.0000x reference)
//
#include <hip/hip_runtime.h>

#define N 4096
#define B 8
#define ITERS 10
#define T (ITERS * N)        // 40960 flat positions; batches never straddle sweeps (16 | 4096)
#define NT 256
#define K 16                 // positions per batch
#define NB (T / K)           // 2560 batches
#define MAXF 6               // prefetched flipped-row slots (overflow handled on demand)

// LDS-only barrier: keeps global prefetch loads in flight (vmcnt untouched).
__device__ __forceinline__ void lds_barrier() {
    asm volatile("s_waitcnt lgkmcnt(0)\n\ts_barrier" ::: "memory");
}

__device__ __forceinline__ unsigned ufl(unsigned v) {
    return (unsigned)__builtin_amdgcn_readfirstlane((int)v);
}

// Kernel 1: Z0[b][i] = sum_j W[i][j] * x[b][j], accumulated in double. (unchanged)
__global__ __launch_bounds__(256) void z0_gemv(const float* __restrict__ W,
                                               const float* __restrict__ x,
                                               double* __restrict__ Z0) {
    const int i = blockIdx.x;
    const int tid = threadIdx.x;
    const int lane = tid & 63;
    const int wid = tid >> 6;
    const float4* __restrict__ row = (const float4*)(W + (size_t)i * N);
    const float4* __restrict__ xv = (const float4*)x;

    double acc[B];
#pragma unroll
    for (int b = 0; b < B; ++b) acc[b] = 0.0;

#pragma unroll
    for (int it = 0; it < 4; ++it) {
        const int c = tid + 256 * it;
        const float4 w = row[c];
#pragma unroll
        for (int b = 0; b < B; ++b) {
            const float4 xb = xv[b * (N / 4) + c];
            acc[b] += (double)w.x * (double)xb.x + (double)w.y * (double)xb.y +
                      (double)w.z * (double)xb.z + (double)w.w * (double)xb.w;
        }
    }

#pragma unroll
    for (int off = 32; off > 0; off >>= 1) {
#pragma unroll
        for (int b = 0; b < B; ++b) acc[b] += __shfl_down(acc[b], off, 64);
    }

    __shared__ double red[4][B];
    if (lane == 0) {
#pragma unroll
        for (int b = 0; b < B; ++b) red[wid][b] = acc[b];
    }
    __syncthreads();
    if (tid < B)
        Z0[(size_t)tid * N + i] = red[0][tid] + red[1][tid] + red[2][tid] + red[3][tid];
}

// Kernel 2: position-order batched replay.
// Per batch i (16 consecutive perm positions, indices known in advance):
//   a) REPLAY: all threads redundantly run the 16 sequential flip decisions
//      using gathered z's (gz) and the within-batch cross block Rq[q][p] =
//      W[j_q][j_p]: on flip q, forward-update z_p (p>q) with d*Rq[q][p].
//      Exact same f64 fma order as the sequential reference.
//   b) APPLY batch i-1: fused z RMW: zz[k] += sum over flipped q (ascending)
//      of d_q * W[j_q][k], rows prefetched last iteration.
//   c) GATHER batch i+1: owners read own z, add batch-i terms via the
//      cross block Xt[p][q] = W[j_q(i)][j_p(i+1)] (same values/order the
//      apply will use -> bit-identical), publish z + current y sign.
//   d/e) cross-block loads for future batches (addresses from perm, issued
//      2 batches ahead, published to LDS 1 batch ahead).
//   f) prefetch flipped rows of batch i (consumed by next iter's apply).
//   One LDS barrier per batch. All flip state is block-uniform (replayed
//   identically by every thread from shared data).
__global__ __launch_bounds__(256) void hop_seq(const float* __restrict__ W,
                                               const float* __restrict__ x,
                                               const int* __restrict__ perms,
                                               const double* __restrict__ Z0,
                                               float* __restrict__ out) {
    const int b = blockIdx.x;
    const int tid = threadIdx.x;
    const int lq = tid >> 4, lp = tid & 15;   // loader role: (q, p) of 16x16 block

    __shared__ double   zL[16][NT];      // z field, SoA: elem j at zL[j&15][j>>4] (32 KB)
    __shared__ float    Rq[2][16][16];   // within-batch cross block, [q][p]
    __shared__ float    Xt[2][16][16];   // next-batch cross block, [p_next][q]
    __shared__ double   gzd[2][16];      // gathered z for replay
    __shared__ unsigned gzs[2][16];      // gathered y sign (1 <=> y=+1)
    __shared__ int      jvL[2][16];      // batch indices (dynamic-q lookup in step f)

    const int* __restrict__ perm_b = perms + (size_t)b * T;

    // ---- init y bits + z field ----
    unsigned ym = 0;
    {
        const float4* __restrict__ xs = (const float4*)(x + (size_t)b * N);
#pragma unroll
        for (int q = 0; q < 4; ++q) {
            const float4 xv = xs[4 * tid + q];
            ym |= (xv.x > 0.f ? 1u : 0u) << (4 * q + 0);
            ym |= (xv.y > 0.f ? 1u : 0u) << (4 * q + 1);
            ym |= (xv.z > 0.f ? 1u : 0u) << (4 * q + 2);
            ym |= (xv.w > 0.f ? 1u : 0u) << (4 * q + 3);
        }
        const double* __restrict__ zsrc = Z0 + (size_t)b * N + 16 * tid;
#pragma unroll
        for (int k = 0; k < 16; ++k) zL[k][tid] = zsrc[k];
    }

    // ---- prologue: batch-0 indices, Rq(0)/Xt(0), gz(0), pend for batch 1 ----
    int jc[16];
#pragma unroll
    for (int q4 = 0; q4 < 4; ++q4) {
        const int4 t4 = ((const int4*)perm_b)[q4];
        jc[4 * q4 + 0] = t4.x; jc[4 * q4 + 1] = t4.y;
        jc[4 * q4 + 2] = t4.z; jc[4 * q4 + 3] = t4.w;
    }
    if (tid < 16) jvL[0][tid] = perm_b[tid];
    {
        const int jq0 = perm_b[lq], jp0 = perm_b[lp], jp1 = perm_b[16 + lp];
        Rq[0][lq][lp] = W[(size_t)jq0 * N + jp0];
        Xt[0][lp][lq] = W[(size_t)jq0 * N + jp1];
    }
#pragma unroll
    for (int p = 0; p < 16; ++p) {
        const int j = jc[p];
        if (tid == (j >> 4)) {
            gzd[0][p] = Z0[(size_t)b * N + j];
            gzs[0][p] = (ym >> (j & 15)) & 1u;
        }
    }
    float pendR, pendX;
    {
        const int jq = perm_b[16 + lq], jp = perm_b[16 + lp], jp2 = perm_b[32 + lp];
        pendR = W[(size_t)jq * N + jp];
        pendX = W[(size_t)jq * N + jp2];
    }
    lds_barrier();

    unsigned fmp = 0, ysp = 0, nfp = 0;  // batch i-1 flip state (block-uniform scalars)
    float4 rows4[MAXF][4];               // prefetched flipped-row slices

#pragma unroll 1
    for (int i = 0; i < NB; ++i) {
        const int pr = i & 1, nx = pr ^ 1;

        // early: batch i+1 indices (broadcast reads) + perm for batch i+2 loads
        int jn[16];
        if (i + 1 < NB) {
#pragma unroll
            for (int q4 = 0; q4 < 4; ++q4) {
                const int4 t4 = ((const int4*)(perm_b + 16 * (i + 1)))[q4];
                jn[4 * q4 + 0] = t4.x; jn[4 * q4 + 1] = t4.y;
                jn[4 * q4 + 2] = t4.z; jn[4 * q4 + 3] = t4.w;
            }
        } else {
#pragma unroll
            for (int p = 0; p < 16; ++p) jn[p] = jc[p];
        }
        int jq_e = 0, jp_e = 0, jp2_e = 0;
        if (i + 2 < NB) {                  // hoisted so step e's W loads don't stall
            const int t2 = 16 * (i + 2);
            jq_e = perm_b[t2 + lq];
            jp_e = perm_b[t2 + lp];
            if (i + 3 < NB) jp2_e = perm_b[t2 + 16 + lp];
        }

        // ---- a: replay batch i (all threads, identical) ----
        double zp[16]; unsigned sg[16];
#pragma unroll
        for (int p = 0; p < 16; ++p) { zp[p] = gzd[pr][p]; sg[p] = gzs[pr][p]; }
        unsigned fm = 0, ys = 0, nf = 0;
#pragma unroll
        for (int q = 0; q < 16; ++q) {
            const unsigned sb = ((unsigned)__double2hiint(zp[q])) >> 31;
            const unsigned fl = 1u ^ sb ^ sg[q];   // flip iff sign(z) mismatches y
            ys |= sg[q] << q;
            if (ufl(fl)) {
                fm |= 1u << q; ++nf;
                const double d = sg[q] ? -2.0 : 2.0;
                const float4* __restrict__ rr = (const float4*)&Rq[pr][q][0];
                const float4 r0 = rr[0], r1 = rr[1], r2 = rr[2], r3 = rr[3];
                const float rv[16] = {r0.x, r0.y, r0.z, r0.w, r1.x, r1.y, r1.z, r1.w,
                                      r2.x, r2.y, r2.z, r2.w, r3.x, r3.y, r3.z, r3.w};
#pragma unroll
                for (int p2 = q + 1; p2 < 16; ++p2)
                    zp[p2] = fma(d, (double)rv[p2], zp[p2]);
            }
        }
        const unsigned fms = ufl(fm), yss = ufl(ys), nfs = ufl(nf);

        // ---- ym update for batch i flips (owners), BEFORE gather publishes signs ----
#pragma unroll
        for (int q = 0; q < 16; ++q) {
            if ((fms >> q) & 1u) {
                const int j = jc[q];
                if (tid == (j >> 4)) ym ^= 1u << (j & 15);
            }
        }

        // ---- b: apply batch i-1 (fused RMW, ascending q = exact sequential order) ----
        if (nfp) {
            double zz[16];
#pragma unroll
            for (int k = 0; k < 16; ++k) zz[k] = zL[k][tid];
            unsigned m = fmp;
#pragma unroll
            for (int s = 0; s < MAXF; ++s) {
                if (s < (int)nfp) {
                    const int q = __ffs(m) - 1; m &= m - 1u;
                    const double d = ((ysp >> q) & 1u) ? -2.0 : 2.0;
#pragma unroll
                    for (int r = 0; r < 4; ++r) {
                        const float4 v = rows4[s][r];
                        zz[4 * r + 0] = fma(d, (double)v.x, zz[4 * r + 0]);
                        zz[4 * r + 1] = fma(d, (double)v.y, zz[4 * r + 1]);
                        zz[4 * r + 2] = fma(d, (double)v.z, zz[4 * r + 2]);
                        zz[4 * r + 3] = fma(d, (double)v.w, zz[4 * r + 3]);
                    }
                }
            }
            if (nfp > MAXF) {                 // rare overflow: load on demand
                for (int s = MAXF; s < (int)nfp; ++s) {
                    const int q = __ffs(m) - 1; m &= m - 1u;
                    const int j = perm_b[16 * (i - 1) + q];
                    const double d = ((ysp >> q) & 1u) ? -2.0 : 2.0;
                    const float4* __restrict__ rp = (const float4*)(W + (size_t)j * N) + 4 * tid;
#pragma unroll
                    for (int r = 0; r < 4; ++r) {
                        const float4 v = rp[r];
                        zz[4 * r + 0] = fma(d, (double)v.x, zz[4 * r + 0]);
                        zz[4 * r + 1] = fma(d, (double)v.y, zz[4 * r + 1]);
                        zz[4 * r + 2] = fma(d, (double)v.z, zz[4 * r + 2]);
                        zz[4 * r + 3] = fma(d, (double)v.w, zz[4 * r + 3]);
                    }
                }
            }
#pragma unroll
            for (int k = 0; k < 16; ++k) zL[k][tid] = zz[k];
        }

        // ---- c: gather batch i+1 (owners; correction == apply's exact chain) ----
        if (i + 1 < NB) {
#pragma unroll
            for (int p = 0; p < 16; ++p) {
                const int j = jn[p];
                if (tid == (j >> 4)) {
                    double zv = zL[j & 15][tid];
                    const float4* __restrict__ xr = (const float4*)&Xt[pr][p][0];
                    const float4 x0 = xr[0], x1 = xr[1], x2 = xr[2], x3 = xr[3];
                    const float xv[16] = {x0.x, x0.y, x0.z, x0.w, x1.x, x1.y, x1.z, x1.w,
                                          x2.x, x2.y, x2.z, x2.w, x3.x, x3.y, x3.z, x3.w};
#pragma unroll
                    for (int q = 0; q < 16; ++q) {
                        if ((fms >> q) & 1u) {
                            const double d = ((yss >> q) & 1u) ? -2.0 : 2.0;
                            zv = fma(d, (double)xv[q], zv);
                        }
                    }
                    gzd[nx][p] = zv;
                    gzs[nx][p] = (ym >> (j & 15)) & 1u;
                }
            }
        }

        // ---- d: publish pending cross blocks for batch i+1 ----
        if (i + 1 < NB) {
            Rq[nx][lq][lp] = pendR;
            Xt[nx][lp][lq] = pendX;
        }
        // ---- e: issue cross-block loads for batch i+2 (stay in flight over barrier) ----
        if (i + 2 < NB) {
            pendR = W[(size_t)jq_e * N + jp_e];
            if (i + 3 < NB) pendX = W[(size_t)jq_e * N + jp2_e];
        }
        // ---- jvL for batch i+1 (used by next iter's step f) ----
        if (tid < 16 && i + 1 < NB) jvL[nx][tid] = perm_b[16 * (i + 1) + tid];

        // ---- f: prefetch flipped rows of batch i (consumed next iter, step b) ----
        if (i + 1 < NB) {
            unsigned m = fms;
#pragma unroll
            for (int s = 0; s < MAXF; ++s) {
                if (s < (int)nfs) {
                    const int q = __ffs(m) - 1; m &= m - 1u;
                    const int j = jvL[pr][q];
                    const float4* __restrict__ rp = (const float4*)(W + (size_t)j * N) + 4 * tid;
                    rows4[s][0] = rp[0]; rows4[s][1] = rp[1];
                    rows4[s][2] = rp[2]; rows4[s][3] = rp[3];
                }
            }
        }

        fmp = fms; ysp = yss; nfp = nfs;
#pragma unroll
        for (int p = 0; p < 16; ++p) jc[p] = jn[p];
        lds_barrier();
    }
    // final batch's z-apply intentionally skipped: output depends only on ym.

    // ---- output: y = +1 if ym bit set else -1 ----
    float4* __restrict__ os = (float4*)(out + (size_t)b * N);
#pragma unroll
    for (int q = 0; q < 4; ++q) {
        float4 o;
        o.x = ((ym >> (4 * q + 0)) & 1u) ? 1.0f : -1.0f;
        o.y = ((ym >> (4 * q + 1)) & 1u) ? 1.0f : -1.0f;
        o.z = ((ym >> (4 * q + 2)) & 1u) ? 1.0f : -1.0f;
        o.w = ((ym >> (4 * q + 3)) & 1u) ? 1.0f : -1.0f;
        os[4 * tid + q] = o;
    }
}

extern "C" void kernel_launch(void* const* d_in, const int* in_sizes, int n_in,
                              void* d_out, int out_size, void* d_ws, size_t ws_size,
                              hipStream_t stream) {
    const float* x = (const float*)d_in[0];      // [B, N] f32, bipolar
    const float* W = (const float*)d_in[1];      // [N, N] f32, symmetric, zero diag
    const int* perms = (const int*)d_in[2];      // [B, ITERS, N] i32
    float* out = (float*)d_out;                  // [B, N] f32
    double* Z0 = (double*)d_ws;                  // B*N doubles = 256 KB scratch

    hipLaunchKernelGGL(z0_gemv, dim3(N), dim3(256), 0, stream, W, x, Z0);
    hipLaunchKernelGGL(hop_seq, dim3(B), dim3(NT), 0, stream, W, x, perms, Z0, out);
}

// Round 5
// 4081.360 us; speedup vs baseline: 2.8566x; 2.8566x over previous
//
#include <hip/hip_runtime.h>

#define N 4096
#define B 8
#define ITERS 10
#define T (ITERS * N)
#define NT 512          // 8 waves
#define E 8             // field elements per thread
#define WIN 1024
#define INFK 0xFFFFFFFFu
#define LIMIT 0x01000000u
#define RCH 260         // floats per ring chunk stride (1040 B: 1 KB data + 16 B pad -> bank-uniform reads)
#define RSLOT (16 * RCH)

// LDS-only barrier: inner-loop cross-wave traffic is LDS slots only ->
// lgkmcnt(0) suffices; in-flight global/ring staging loads stay in flight.
__device__ __forceinline__ void lds_barrier() {
    asm volatile("s_waitcnt lgkmcnt(0)\n\ts_barrier" ::: "memory");
}

// Kernel 1: Z0[b][i] = sum_j W[i][j] * x[b][j], accumulated in double. (proven)
__global__ __launch_bounds__(256) void z0_gemv(const float* __restrict__ W,
                                               const float* __restrict__ x,
                                               double* __restrict__ Z0) {
    const int i = blockIdx.x;
    const int tid = threadIdx.x;
    const int lane = tid & 63;
    const int wid = tid >> 6;
    const float4* __restrict__ row = (const float4*)(W + (size_t)i * N);
    const float4* __restrict__ xv = (const float4*)x;

    double acc[B];
#pragma unroll
    for (int b = 0; b < B; ++b) acc[b] = 0.0;

#pragma unroll
    for (int it = 0; it < 4; ++it) {
        const int c = tid + 256 * it;
        const float4 w = row[c];
#pragma unroll
        for (int b = 0; b < B; ++b) {
            const float4 xb = xv[b * (N / 4) + c];
            acc[b] += (double)w.x * (double)xb.x + (double)w.y * (double)xb.y +
                      (double)w.z * (double)xb.z + (double)w.w * (double)xb.w;
        }
    }

#pragma unroll
    for (int off = 32; off > 0; off >>= 1) {
#pragma unroll
        for (int b = 0; b < B; ++b) acc[b] += __shfl_down(acc[b], off, 64);
    }

    __shared__ double red[4][B];
    if (lane == 0) {
#pragma unroll
        for (int b = 0; b < B; ++b) red[wid][b] = acc[b];
    }
    __syncthreads();
    if (tid < B)
        Z0[(size_t)tid * N + i] = red[0][tid] + red[1][tid] + red[2][tid] + red[3][tid];
}

__device__ __forceinline__ unsigned umin2(unsigned a, unsigned b) { return a < b ? a : b; }

template <int CTRL>
__device__ __forceinline__ unsigned dpp_min(unsigned v) {
    const int t = __builtin_amdgcn_update_dpp((int)v, (int)v, CTRL, 0xF, 0xF, false);
    return umin2(v, (unsigned)t);
}

// Full wave64 min via DPP; wave-uniform result via readlane(63). (proven)
__device__ __forceinline__ unsigned wave_min64(unsigned v) {
    v = dpp_min<0x111>(v);  // row_shr:1
    v = dpp_min<0x112>(v);  // row_shr:2
    v = dpp_min<0x114>(v);  // row_shr:4
    v = dpp_min<0x118>(v);  // row_shr:8
    v = dpp_min<0x142>(v);  // row_bcast:15
    v = dpp_min<0x143>(v);  // row_bcast:31
    return (unsigned)__builtin_amdgcn_readlane((int)v, 63);
}

// Stage one W row into ring slot via async global->LDS DMA.
// Wave wv stages its own 2 chunks (the bytes its threads will read back):
// chunk c covers floats [c*256, c*256+256); reader t (in wave t>>6) reads
// floats [8t, 8t+8) -> chunks {2*wv, 2*wv+1}. LDS dest = uniform base +
// lane*16 (HW rule); global src = per-lane base + lane*16.
__device__ __forceinline__ void stage_row(const float* __restrict__ W, int j,
                                          float* ringbase, int slot, int wv, int lane) {
    const float* g0 = W + (size_t)j * N + (2 * wv) * 256 + lane * 4;
    const float* g1 = W + (size_t)j * N + (2 * wv + 1) * 256 + lane * 4;
    float* l0 = ringbase + slot * RSLOT + (2 * wv) * RCH;
    float* l1 = ringbase + slot * RSLOT + (2 * wv + 1) * RCH;
    __builtin_amdgcn_global_load_lds((const __attribute__((address_space(1))) void*)g0,
                                     (__attribute__((address_space(3))) void*)l0, 16, 0, 0);
    __builtin_amdgcn_global_load_lds((const __attribute__((address_space(1))) void*)g1,
                                     (__attribute__((address_space(3))) void*)l1, 16, 0, 0);
}

// Kernel 2: proven min-key scan (round-0/1 structure) + position-ordered
// LDS row ring. Ring holds rows of the next 8 unvisited perm positions
// [cursor, cursor+8). Winner = first mismatched position -> in ring w.p.
// ~77%. Hit: row fragment from LDS (~120cy) instead of global (~450cy).
// Staging is async (global_load_lds) with addresses known >=1 flip ahead.
// Key algebra unchanged: sk = pos<<14 | i<<2 | (y+1); per elem per round:
//  zj += d*w; t2 = hi64(zj) ^ ymask; cand = (sk | (t2>>31)) - ck; min.
__global__ __launch_bounds__(512) void hop_seq(const float* __restrict__ W,
                                               const float* __restrict__ x,
                                               const int* __restrict__ perms,
                                               const double* __restrict__ Z0,
                                               float* __restrict__ out) {
    const int b = blockIdx.x;
    const int tid = threadIdx.x;
    const int wv = tid >> 6;
    const int lane = tid & 63;

    __shared__ int wpos[N];                         // 16 KB epoch-tagged inverse map
    __shared__ float ring[8 * RSLOT];               // 130 KB row ring (8 slots)
    __shared__ __align__(16) unsigned slot1[2][8];  // per-wave min, parity buffered

    // ---- register-resident field ----
    double zj[E];
    unsigned ymask[E];             // 0xFFFFFFFF if y>0 else 0x7FFFFFFF
    unsigned sk[E];
    {
        const double* __restrict__ zsrc = Z0 + (size_t)b * N + E * tid;
#pragma unroll
        for (int k = 0; k < E; ++k) zj[k] = zsrc[k];
        const float4* __restrict__ xs = (const float4*)(x + (size_t)b * N);
#pragma unroll
        for (int q = 0; q < 2; ++q) {
            const float4 xv = xs[2 * tid + q];
            ymask[4 * q + 0] = (xv.x > 0.f) ? 0xFFFFFFFFu : 0x7FFFFFFFu;
            ymask[4 * q + 1] = (xv.y > 0.f) ? 0xFFFFFFFFu : 0x7FFFFFFFu;
            ymask[4 * q + 2] = (xv.z > 0.f) ? 0xFFFFFFFFu : 0x7FFFFFFFu;
            ymask[4 * q + 3] = (xv.w > 0.f) ? 0xFFFFFFFFu : 0x7FFFFFFFu;
        }
    }
    // zero-init inverse map (stale-tag hazard: LDS is undefined at start)
    {
        const int4 z4 = make_int4(0, 0, 0, 0);
        ((int4*)wpos)[tid] = z4;
        ((int4*)wpos)[tid + 512] = z4;
    }
    lds_barrier();

    const int* __restrict__ perm_b = perms + (size_t)b * T;
    unsigned r = 0;                // barrier parity counter

    for (int base = 0; base < T; base += WIN) {
        const int epoch = (base >> 10) + 1;
        // scatter inverse map (window = permutation slice, indices distinct)
        const int2 iv = ((const int2*)(perm_b + base))[tid];
        wpos[iv.x] = (epoch << 10) | (2 * tid);
        wpos[iv.y] = (epoch << 10) | (2 * tid + 1);

        // ---- prologue staging: rows of positions 0..7 into the ring ----
        int pj[8];
#pragma unroll
        for (int q = 0; q < 8; ++q) pj[q] = perm_b[base + q];
        // drain any stale in-flight stagings from the previous window before
        // overwriting the same slots (DMA write ordering is not guaranteed)
        asm volatile("s_waitcnt vmcnt(0)" ::: "memory");
#pragma unroll
        for (int q = 0; q < 8; ++q) stage_row(W, pj[q], ring, q, wv, lane);
        lds_barrier();

        // build static keys for the 8 owned elems
#pragma unroll
        for (int q = 0; q < 2; ++q) {
            const int4 wp = ((const int4*)wpos)[2 * tid + q];
            const int e0 = 4 * q;
            const unsigned i0 = (unsigned)(E * tid + e0);
            sk[e0 + 0] = ((wp.x >> 10) == epoch)
                ? (((unsigned)(wp.x & 1023) << 14) | ((i0 + 0) << 2) | ((ymask[e0 + 0] >> 30) & 2u)) : INFK;
            sk[e0 + 1] = ((wp.y >> 10) == epoch)
                ? (((unsigned)(wp.y & 1023) << 14) | ((i0 + 1) << 2) | ((ymask[e0 + 1] >> 30) & 2u)) : INFK;
            sk[e0 + 2] = ((wp.z >> 10) == epoch)
                ? (((unsigned)(wp.z & 1023) << 14) | ((i0 + 2) << 2) | ((ymask[e0 + 2] >> 30) & 2u)) : INFK;
            sk[e0 + 3] = ((wp.w >> 10) == epoch)
                ? (((unsigned)(wp.w & 1023) << 14) | ((i0 + 3) << 2) | ((ymask[e0 + 3] >> 30) & 2u)) : INFK;
        }

        unsigned ck = 0;
        // round-0 pure scan
        unsigned key = INFK;
#pragma unroll
        for (int k = 0; k < E; ++k) {
            const unsigned t2 = ((unsigned)__double2hiint(zj[k])) ^ ymask[k];
            key = umin2(key, sk[k] | (unsigned)(((int)t2) >> 31));
        }

        int shi = 8;                   // staged-or-deferred frontier (positions [0,shi))
        int dpos = -1, dj = 0;         // deferred staging (issued next round-start)

        for (;;) {
            const unsigned m1 = wave_min64(key);
            const unsigned p = r & 1u; ++r;
            if (lane == 0) slot1[p][wv] = m1;
            // issue deferred staging while the barrier settles; its slot's
            // previous read is >=1 barrier old (lgkm-drained) -> no race
            const bool dissued = (dpos >= 0);
            if (dissued) stage_row(W, dj, ring, dpos & 7, wv, lane);
            lds_barrier();

            const uint4 sa = ((const uint4*)&slot1[p][0])[0];
            const uint4 sb = ((const uint4*)&slot1[p][0])[1];
            const unsigned g = umin2(umin2(umin2(sa.x, sa.y), umin2(sa.z, sa.w)),
                                     umin2(umin2(sb.x, sb.y), umin2(sb.z, sb.w)));
            if (g >= LIMIT) break;     // window converged (uniform)

            const unsigned wk = g + ck;
            const int pstar = (int)(wk >> 14);
            const int istar = (int)((wk >> 2) & 4095u);
            const double d = (double)(-2 * ((int)(wk & 3u) - 1));
            ck = ((wk >> 14) + 1u) << 14;

            // ---- winner row: LDS ring on hit, direct global on miss ----
            float wr[E];
            const bool hit = (pstar < shi);   // uniform
            if (hit) {
                if (dissued && pstar == dpos)
                    asm volatile("s_waitcnt vmcnt(0)" ::: "memory");   // reading the just-issued slot
                else if (dissued)
                    asm volatile("s_waitcnt vmcnt(2)" ::: "memory");   // allow deferred's 2 DMAs to float
                else
                    asm volatile("s_waitcnt vmcnt(0)" ::: "memory");
                const float4* __restrict__ rp =
                    (const float4*)&ring[(pstar & 7) * RSLOT + (tid >> 5) * RCH + (tid & 31) * 8];
                const float4 v0 = rp[0], v1 = rp[1];
                wr[0] = v0.x; wr[1] = v0.y; wr[2] = v0.z; wr[3] = v0.w;
                wr[4] = v1.x; wr[5] = v1.y; wr[6] = v1.z; wr[7] = v1.w;
            } else {
                const float4* __restrict__ rp = (const float4*)(W + (size_t)istar * N) + 2 * tid;
                const float4 v0 = rp[0], v1 = rp[1];
                wr[0] = v0.x; wr[1] = v0.y; wr[2] = v0.z; wr[3] = v0.w;
                wr[4] = v1.x; wr[5] = v1.y; wr[6] = v1.z; wr[7] = v1.w;
            }

            // ---- issue perm loads for the new stage range (hide under apply) ----
            const int lo = max(shi, pstar + 1);
            const int hi = min(pstar + 9, WIN);
            int jq[7];
#pragma unroll
            for (int s = 0; s < 7; ++s)
                if (lo + s < hi - 1) jq[s] = perm_b[base + lo + s];
            const int djn = perm_b[base + hi - 1];

            // ---- owner fixup (1 thread) ----
            if (tid == (istar >> 3)) {
                const int kk = istar & 7;
#pragma unroll
                for (int k = 0; k < E; ++k)
                    if (k == kk) { ymask[k] ^= 0x80000000u; sk[k] ^= 2u; }
            }

            // ---- fused apply + scan for next winner ----
            key = INFK;
#pragma unroll
            for (int k = 0; k < E; ++k) {
                zj[k] += d * (double)wr[k];   // W[istar][istar]==0 -> owner safe
                const unsigned t2 = ((unsigned)__double2hiint(zj[k])) ^ ymask[k];
                const unsigned cand = (sk[k] | (unsigned)(((int)t2) >> 31)) - ck;
                key = umin2(key, cand);
            }

            // ---- stage new ring rows [lo, hi-1); defer hi-1 to next round ----
            if (!hit)  // miss restages many slots at once: drain old DMAs first
                asm volatile("s_waitcnt vmcnt(0)" ::: "memory");
#pragma unroll
            for (int s = 0; s < 7; ++s) {
                const int q = lo + s;
                if (q < hi - 1) stage_row(W, jq[s], ring, q & 7, wv, lane);
            }
            if (hi - 1 >= lo) { dpos = hi - 1; dj = djn; }
            else              { dpos = -1; }
            shi = hi;
        }
    }

    // ---- output: y = +1 if ymask top bit set else -1 ----
    float4* __restrict__ os = (float4*)(out + (size_t)b * N);
#pragma unroll
    for (int q = 0; q < 2; ++q) {
        float4 o;
        o.x = (ymask[4 * q + 0] & 0x80000000u) ? 1.0f : -1.0f;
        o.y = (ymask[4 * q + 1] & 0x80000000u) ? 1.0f : -1.0f;
        o.z = (ymask[4 * q + 2] & 0x80000000u) ? 1.0f : -1.0f;
        o.w = (ymask[4 * q + 3] & 0x80000000u) ? 1.0f : -1.0f;
        os[2 * tid + q] = o;
    }
}

extern "C" void kernel_launch(void* const* d_in, const int* in_sizes, int n_in,
                              void* d_out, int out_size, void* d_ws, size_t ws_size,
                              hipStream_t stream) {
    const float* x = (const float*)d_in[0];      // [B, N] f32, bipolar
    const float* W = (const float*)d_in[1];      // [N, N] f32, symmetric, zero diag
    const int* perms = (const int*)d_in[2];      // [B, ITERS, N] i32
    float* out = (float*)d_out;                  // [B, N] f32
    double* Z0 = (double*)d_ws;                  // B*N doubles = 256 KB scratch

    hipLaunchKernelGGL(z0_gemv, dim3(N), dim3(256), 0, stream, W, x, Z0);
    hipLaunchKernelGGL(hop_seq, dim3(B), dim3(NT), 0, stream, W, x, perms, Z0, out);
}

// Round 6
// 2324.262 us; speedup vs baseline: 5.0161x; 1.7560x over previous
//
#include <hip/hip_runtime.h>

#define N 4096
#define B 8
#define ITERS 10
#define T (ITERS * N)
#define NT 256          // 4 waves
#define E 16            // field elements per thread
#define WIN 1024
#define INFK 0xFFFFFFFFu
#define LIMIT 0x01000000u   // 1024<<14: max valid relative key span

// LDS-only barrier: inner-loop cross-wave traffic is LDS slots only ->
// lgkmcnt(0) suffices; in-flight global row loads stay in flight.
// Parity-buffered slots + 1 barrier/round is race-free (reuse of a slot is
// separated by >= 2 barriers; read < bar(t+1) < rewrite ordering).
__device__ __forceinline__ void lds_barrier() {
    asm volatile("s_waitcnt lgkmcnt(0)\n\ts_barrier" ::: "memory");
}

// Kernel 1: Z0[b][i] = sum_j W[i][j] * x[b][j], accumulated in double. (proven)
__global__ __launch_bounds__(256) void z0_gemv(const float* __restrict__ W,
                                               const float* __restrict__ x,
                                               double* __restrict__ Z0) {
    const int i = blockIdx.x;
    const int tid = threadIdx.x;
    const int lane = tid & 63;
    const int wid = tid >> 6;
    const float4* __restrict__ row = (const float4*)(W + (size_t)i * N);
    const float4* __restrict__ xv = (const float4*)x;

    double acc[B];
#pragma unroll
    for (int b = 0; b < B; ++b) acc[b] = 0.0;

#pragma unroll
    for (int it = 0; it < 4; ++it) {
        const int c = tid + 256 * it;
        const float4 w = row[c];
#pragma unroll
        for (int b = 0; b < B; ++b) {
            const float4 xb = xv[b * (N / 4) + c];
            acc[b] += (double)w.x * (double)xb.x + (double)w.y * (double)xb.y +
                      (double)w.z * (double)xb.z + (double)w.w * (double)xb.w;
        }
    }

#pragma unroll
    for (int off = 32; off > 0; off >>= 1) {
#pragma unroll
        for (int b = 0; b < B; ++b) acc[b] += __shfl_down(acc[b], off, 64);
    }

    __shared__ double red[4][B];
    if (lane == 0) {
#pragma unroll
        for (int b = 0; b < B; ++b) red[wid][b] = acc[b];
    }
    __syncthreads();
    if (tid < B)
        Z0[(size_t)tid * N + i] = red[0][tid] + red[1][tid] + red[2][tid] + red[3][tid];
}

__device__ __forceinline__ unsigned umin2(unsigned a, unsigned b) { return a < b ? a : b; }

template <int CTRL>
__device__ __forceinline__ unsigned dpp_min(unsigned v) {
    const int t = __builtin_amdgcn_update_dpp((int)v, (int)v, CTRL, 0xF, 0xF, false);
    return umin2(v, (unsigned)t);
}

// Full wave64 min via DPP; wave-uniform result via readlane(63). (proven)
__device__ __forceinline__ unsigned wave_min64(unsigned v) {
    v = dpp_min<0x111>(v);  // row_shr:1
    v = dpp_min<0x112>(v);  // row_shr:2
    v = dpp_min<0x114>(v);  // row_shr:4
    v = dpp_min<0x118>(v);  // row_shr:8
    v = dpp_min<0x142>(v);  // row_bcast:15
    v = dpp_min<0x143>(v);  // row_bcast:31
    return (unsigned)__builtin_amdgcn_readlane((int)v, 63);
}

// Load this thread's 16-column fragment of row i into registers.
__device__ __forceinline__ void fetch_row(const float* __restrict__ W, int i,
                                          int tid, float* wr) {
    const float4* __restrict__ rp = (const float4*)(W + (size_t)i * N) + 4 * tid;
    const float4 a = rp[0], c = rp[1], e = rp[2], f = rp[3];
    wr[0] = a.x;  wr[1] = a.y;  wr[2] = a.z;  wr[3] = a.w;
    wr[4] = c.x;  wr[5] = c.y;  wr[6] = c.z;  wr[7] = c.w;
    wr[8] = e.x;  wr[9] = e.y;  wr[10] = e.z; wr[11] = e.w;
    wr[12] = f.x; wr[13] = f.y; wr[14] = f.z; wr[15] = f.w;
}

// Kernel 2: pair-commit rounds. Each round commits the top-2 candidates
// (i1 at pos1, i2 at pos2) speculatively in ONE coordination phase:
//   fused pass: zm = z + d1*w1 (mid), zj = zm + d2*w2 (post);
//     keyP = min post-candidate (rel ckP = pos2+1)     -> next pair
//     vmin = min over pos in (pos1,pos2] of mid-keys   -> validity
//   i2's fixup is pre-applied, so its vmin entry is sign-INVERTED: it
//   contributes only if i2 DE-mismatched at mid. Hence
//     success <=> gvmin >= gapspan  (no interloper AND i2 still mismatched).
//   Failure: bit-exact rollback to zm (i1 stays committed), revert i2 fixup;
//     interloper case -> its key IS the true next winner (solo round);
//     de-mismatch case -> scan-only round from mid state.
// Unified round runs 2/1/0-flip variants (f2/f1/scan) through one path.
// Key algebra unchanged: sk = pos<<14 | i<<2 | (y+1); cand = (sk|sext)-ck.
// Exactness: success z = fma(d2,w2,fma(d1,w1,z)) = the sequential two-apply
// chain; failure z = zm = exact single apply. Same ops, same order.
__global__ __launch_bounds__(256) void hop_seq(const float* __restrict__ W,
                                               const float* __restrict__ x,
                                               const int* __restrict__ perms,
                                               const double* __restrict__ Z0,
                                               float* __restrict__ out) {
    const int b = blockIdx.x;
    const int tid = threadIdx.x;
    const int wid = tid >> 6;
    const int lane = tid & 63;

    __shared__ int wpos[N];                       // 16 KB epoch-tagged inverse map
    __shared__ __align__(16) unsigned aP1[2][4];  // per-wave post min, parity buffered
    __shared__ __align__(16) unsigned aP2[2][4];  // per-wave post 2nd min
    __shared__ __align__(16) unsigned aV[2][4];   // per-wave gap-validity min

    // ---- register-resident field ----
    double zj[E], zm[E];
    unsigned ym[E];                // 0xFFFFFFFF if y>0 else 0x7FFFFFFF
    unsigned sk[E];
    {
        const double* __restrict__ zsrc = Z0 + (size_t)b * N + E * tid;
#pragma unroll
        for (int k = 0; k < E; ++k) zj[k] = zsrc[k];
        const float4* __restrict__ xs = (const float4*)(x + (size_t)b * N);
#pragma unroll
        for (int q = 0; q < 4; ++q) {
            const float4 xv = xs[4 * tid + q];
            ym[4 * q + 0] = (xv.x > 0.f) ? 0xFFFFFFFFu : 0x7FFFFFFFu;
            ym[4 * q + 1] = (xv.y > 0.f) ? 0xFFFFFFFFu : 0x7FFFFFFFu;
            ym[4 * q + 2] = (xv.z > 0.f) ? 0xFFFFFFFFu : 0x7FFFFFFFu;
            ym[4 * q + 3] = (xv.w > 0.f) ? 0xFFFFFFFFu : 0x7FFFFFFFu;
        }
    }
    // zero-init inverse map (stale-tag hazard: LDS undefined at start)
    {
        const int4 z4 = make_int4(0, 0, 0, 0);
#pragma unroll
        for (int q = 0; q < 4; ++q) ((int4*)wpos)[tid + 256 * q] = z4;
    }
    lds_barrier();

    const int* __restrict__ perm_b = perms + (size_t)b * T;
    unsigned r = 0;                // barrier parity counter

    for (int base = 0; base < T; base += WIN) {
        const int epoch = (base >> 10) + 1;
        // scatter inverse map (window = permutation slice, indices distinct)
        const int4 iv = ((const int4*)(perm_b + base))[tid];
        wpos[iv.x] = (epoch << 10) | (4 * tid + 0);
        wpos[iv.y] = (epoch << 10) | (4 * tid + 1);
        wpos[iv.z] = (epoch << 10) | (4 * tid + 2);
        wpos[iv.w] = (epoch << 10) | (4 * tid + 3);
        lds_barrier();
        // build static keys for the 16 owned elems
#pragma unroll
        for (int q = 0; q < 4; ++q) {
            const int4 wp = ((const int4*)wpos)[4 * tid + q];
            const int e0 = 4 * q;
            const unsigned i0 = (unsigned)(E * tid + e0);
            sk[e0 + 0] = ((wp.x >> 10) == epoch)
                ? (((unsigned)(wp.x & 1023) << 14) | ((i0 + 0) << 2) | ((ym[e0 + 0] >> 30) & 2u)) : INFK;
            sk[e0 + 1] = ((wp.y >> 10) == epoch)
                ? (((unsigned)(wp.y & 1023) << 14) | ((i0 + 1) << 2) | ((ym[e0 + 1] >> 30) & 2u)) : INFK;
            sk[e0 + 2] = ((wp.z >> 10) == epoch)
                ? (((unsigned)(wp.z & 1023) << 14) | ((i0 + 2) << 2) | ((ym[e0 + 2] >> 30) & 2u)) : INFK;
            sk[e0 + 3] = ((wp.w >> 10) == epoch)
                ? (((unsigned)(wp.w & 1023) << 14) | ((i0 + 3) << 2) | ((ym[e0 + 3] >> 30) & 2u)) : INFK;
        }

        unsigned f1 = 0, f2v = 0;          // how many flips this round carries
        unsigned awk1 = 0, awk2 = 0;       // absolute keys of the pair
        unsigned ckR = 0;                  // resume cursor for scan-only rounds
        float w1[E], w2[E];

        for (;;) {
            // ---- uniform decode + owner fixups ----
            unsigned ckP, ckM = 0, gspan = 0;
            int i1 = 0, i2 = 0;
            double d1 = 0.0, d2 = 0.0;
            if (f1) {
                i1 = (int)((awk1 >> 2) & 4095u);
                d1 = (double)(-2 * ((int)(awk1 & 3u) - 1));
                if (f2v) {
                    i2 = (int)((awk2 >> 2) & 4095u);
                    d2 = (double)(-2 * ((int)(awk2 & 3u) - 1));
                    ckM = ((awk1 >> 14) + 1u) << 14;
                    ckP = ((awk2 >> 14) + 1u) << 14;
                    gspan = ckP - ckM;
                    if (tid == (i2 >> 4)) {
                        const int kk = i2 & 15;
#pragma unroll
                        for (int k = 0; k < E; ++k)
                            if (k == kk) { ym[k] ^= 0x80000000u; sk[k] ^= 2u; }
                    }
                } else {
                    ckP = ((awk1 >> 14) + 1u) << 14;
                }
                if (tid == (i1 >> 4)) {
                    const int kk = i1 & 15;
#pragma unroll
                    for (int k = 0; k < E; ++k)
                        if (k == kk) { ym[k] ^= 0x80000000u; sk[k] ^= 2u; }
                }
            } else {
                ckP = ckR;
            }

            // ---- fused pass: mid + post + keyP + vmin ----
            unsigned keyP = INFK, vmin = INFK;
            if (f2v) {
#pragma unroll
                for (int k = 0; k < E; ++k) {
                    const double a = fma(d1, (double)w1[k], zj[k]);   // mid
                    zm[k] = a;
                    const unsigned tm = ((unsigned)__double2hiint(a)) ^ ym[k];
                    const unsigned cM = sk[k] | (unsigned)(((int)tm) >> 31);
                    vmin = umin2(vmin, cM - ckM);
                    const double c = fma(d2, (double)w2[k], a);       // post
                    zj[k] = c;
                    const unsigned tp = ((unsigned)__double2hiint(c)) ^ ym[k];
                    keyP = umin2(keyP, (sk[k] | (unsigned)(((int)tp) >> 31)) - ckP);
                }
            } else if (f1) {
#pragma unroll
                for (int k = 0; k < E; ++k) {
                    const double c = fma(d1, (double)w1[k], zj[k]);
                    zj[k] = c;
                    const unsigned tp = ((unsigned)__double2hiint(c)) ^ ym[k];
                    keyP = umin2(keyP, (sk[k] | (unsigned)(((int)tp) >> 31)) - ckP);
                }
            } else {
#pragma unroll
                for (int k = 0; k < E; ++k) {
                    const unsigned tp = ((unsigned)__double2hiint(zj[k])) ^ ym[k];
                    keyP = umin2(keyP, (sk[k] | (unsigned)(((int)tp) >> 31)) - ckP);
                }
            }

            // ---- trees: post top-2 (serial) + validity (independent) ----
            const unsigned m1 = wave_min64(keyP);
            const unsigned mv = f2v ? wave_min64(vmin) : INFK;
            const unsigned m2 = wave_min64(keyP == m1 ? INFK : keyP);

            // ---- publish, ONE barrier, read, resolve ----
            const unsigned p = r & 1u; ++r;
            if (lane == 0) { aP1[p][wid] = m1; aP2[p][wid] = m2; aV[p][wid] = mv; }
            lds_barrier();
            const uint4 P1 = *(const uint4*)&aP1[p][0];
            const unsigned gP = umin2(umin2(P1.x, P1.y), umin2(P1.z, P1.w));
            if (f2v) {
                const uint4 V4 = *(const uint4*)&aV[p][0];
                const unsigned gV = umin2(umin2(V4.x, V4.y), umin2(V4.z, V4.w));
                if (gV < gspan) {
                    // ---- FAILURE: rollback to mid, revert i2 ----
#pragma unroll
                    for (int k = 0; k < E; ++k) zj[k] = zm[k];
                    if (tid == (i2 >> 4)) {
                        const int kk = i2 & 15;
#pragma unroll
                        for (int k = 0; k < E; ++k)
                            if (k == kk) { ym[k] ^= 0x80000000u; sk[k] ^= 2u; }
                    }
                    const unsigned vabs = gV + ckM;
                    if ((vabs >> 14) == (awk2 >> 14)) {
                        // case b: i2 de-mismatched; fresh scan from mid state
                        f1 = 0; f2v = 0; ckR = ckM;
                    } else {
                        // case a: interloper IS the true next winner (solo)
                        awk1 = vabs; f1 = 1; f2v = 0;
                        fetch_row(W, (int)((awk1 >> 2) & 4095u), tid, w1);
                    }
                    continue;
                }
            }
            // ---- SUCCESS / normal advance ----
            if (gP >= LIMIT) break;       // window converged
            awk1 = gP + ckP; f1 = 1;
            fetch_row(W, (int)((awk1 >> 2) & 4095u), tid, w1);
            const uint4 P2 = *(const uint4*)&aP2[p][0];
            const unsigned o0 = (P1.x == gP) ? P2.x : P1.x;
            const unsigned o1 = (P1.y == gP) ? P2.y : P1.y;
            const unsigned o2 = (P1.z == gP) ? P2.z : P1.z;
            const unsigned o3 = (P1.w == gP) ? P2.w : P1.w;
            const unsigned gP2 = umin2(umin2(o0, o1), umin2(o2, o3));
            f2v = (gP2 < LIMIT) ? 1u : 0u;
            if (f2v) {
                awk2 = gP2 + ckP;
                fetch_row(W, (int)((awk2 >> 2) & 4095u), tid, w2);
            }
        }
    }

    // ---- output: y = +1 if ym top bit set else -1 ----
    float4* __restrict__ os = (float4*)(out + (size_t)b * N);
#pragma unroll
    for (int q = 0; q < 4; ++q) {
        float4 o;
        o.x = (ym[4 * q + 0] & 0x80000000u) ? 1.0f : -1.0f;
        o.y = (ym[4 * q + 1] & 0x80000000u) ? 1.0f : -1.0f;
        o.z = (ym[4 * q + 2] & 0x80000000u) ? 1.0f : -1.0f;
        o.w = (ym[4 * q + 3] & 0x80000000u) ? 1.0f : -1.0f;
        os[4 * tid + q] = o;
    }
}

extern "C" void kernel_launch(void* const* d_in, const int* in_sizes, int n_in,
                              void* d_out, int out_size, void* d_ws, size_t ws_size,
                              hipStream_t stream) {
    const float* x = (const float*)d_in[0];      // [B, N] f32, bipolar
    const float* W = (const float*)d_in[1];      // [N, N] f32, symmetric, zero diag
    const int* perms = (const int*)d_in[2];      // [B, ITERS, N] i32
    float* out = (float*)d_out;                  // [B, N] f32
    double* Z0 = (double*)d_ws;                  // B*N doubles = 256 KB scratch

    hipLaunchKernelGGL(z0_gemv, dim3(N), dim3(256), 0, stream, W, x, Z0);
    hipLaunchKernelGGL(hop_seq, dim3(B), dim3(NT), 0, stream, W, x, perms, Z0, out);
}